// Round 3
// baseline (190.940 us; speedup 1.0000x reference)
//
#include <hip/hip_runtime.h>

// Carry-save adder over {0,1}-valued floats == exact 16-bit integer circuit.
//
//   in0 = bits(x[:,0]); tc = bits(x[:,1]); cnt = 0
//   for i in 2..L-1:   (keep = mask[i] > 0)
//     s = in0 ^ xi ^ tc;  c = maj(in0, xi, tc)
//     if keep: cnt += bit15(c); in0 = s; tc = (c << 1) & 0xFFFF
//   sum = in0 + tc   (ripple-carry adder == integer add)
//   output bits = sum & 0xFFFF;  carry = cnt + bit16(sum)

#define RPB 32            // rows per block
#define LSTRIDE 68        // LDS row stride in ushorts: 136 B == 2 dwords mod 32 banks -> 2-way (free)

// ---------------- Fused kernel (L == 64, B % RPB == 0) ----------------
__global__ __launch_bounds__(256) void csa_fused_block(const float* __restrict__ x,
                                                       const int* __restrict__ mask,
                                                       float* __restrict__ out,
                                                       float* __restrict__ carry_out,
                                                       int B) {
    // Full 64-bit keep mask in a register: 1 load + 1 ballot (all lanes active).
    unsigned long long keepmask = __ballot(mask[threadIdx.x & 63] > 0);

    __shared__ unsigned short sl[RPB * LSTRIDE];

    const int r0 = blockIdx.x * RPB;
    // Block input region: RPB rows * 64 slices * 4 float4 = 8192 float4 (128 KB).
    const float4* base = reinterpret_cast<const float4*>(x) + (size_t)r0 * 256;

    // ---- Phase 1: coalesced pack. Consecutive lanes read consecutive 16 B. ----
#pragma unroll 4
    for (int it = 0; it < (RPB * 256) / 256; ++it) {
        int idx = it * 256 + (int)threadIdx.x;      // float4 index in block region
        float4 f = base[idx];
        unsigned nib = (f.x != 0.f ? 1u : 0u) | (f.y != 0.f ? 2u : 0u)
                     | (f.z != 0.f ? 4u : 0u) | (f.w != 0.f ? 8u : 0u);
        int q = idx & 3;                            // quarter of the 16-bit slice
        unsigned v = nib << (q * 4);
        v |= __shfl_xor(v, 1);                      // combine 4 consecutive lanes
        v |= __shfl_xor(v, 2);                      // (they share one slice)
        if (q == 0) {
            int s  = idx >> 2;                      // slice within block [0, RPB*64)
            int rr = s >> 6, si = s & 63;
            sl[rr * LSTRIDE + si] = (unsigned short)v;
        }
    }
    __syncthreads();

    // ---- Phase 2: one thread per row runs the 62-step bit circuit. ----
    int tid = threadIdx.x;
    if (tid < RPB) {
        // 64 ushorts = 32 words, read as 16x uint2 (8B-aligned; stride 136 B).
        const uint2* rp = reinterpret_cast<const uint2*>(&sl[tid * LSTRIDE]);
        unsigned w[32];
#pragma unroll
        for (int k = 0; k < 16; ++k) {
            uint2 v = rp[k];
            w[2 * k] = v.x; w[2 * k + 1] = v.y;
        }

        unsigned in0 = w[0] & 0xFFFFu;
        unsigned tc  = (w[0] >> 16) & 0xFFFFu;
        unsigned cnt = 0;

#pragma unroll
        for (int i = 2; i < 64; ++i) {              // compile-time i -> w[] in regs
            unsigned xi = (w[i >> 1] >> ((i & 1) * 16)) & 0xFFFFu;
            unsigned s  = in0 ^ xi ^ tc;
            unsigned c  = (in0 & xi) | (tc & (in0 | xi));   // majority
            if ((keepmask >> i) & 1ull) {
                cnt += (c >> 15) & 1u;
                in0 = s;
                tc  = (c << 1) & 0xFFFFu;
            }
        }

        unsigned sum = in0 + tc;                    // ripple-carry == int add
        cnt += (sum >> 16) & 1u;

        int r = r0 + tid;
        float4* orow = reinterpret_cast<float4*>(out + (size_t)r * 16);
#pragma unroll
        for (int q = 0; q < 4; ++q) {
            float4 o;
            o.x = (float)((sum >> (q * 4 + 0)) & 1u);
            o.y = (float)((sum >> (q * 4 + 1)) & 1u);
            o.z = (float)((sum >> (q * 4 + 2)) & 1u);
            o.w = (float)((sum >> (q * 4 + 3)) & 1u);
            orow[q] = o;
        }
        carry_out[r] = (float)cnt;
    }
}

// ---------------- Fallback: thread-per-row, general L ------------------
__device__ __forceinline__ unsigned pack16(const float4* __restrict__ p) {
    float4 f0 = p[0], f1 = p[1], f2 = p[2], f3 = p[3];
    float acc = f0.x;
    acc = fmaf(f0.y,     2.f, acc);
    acc = fmaf(f0.z,     4.f, acc);
    acc = fmaf(f0.w,     8.f, acc);
    acc = fmaf(f1.x,    16.f, acc);
    acc = fmaf(f1.y,    32.f, acc);
    acc = fmaf(f1.z,    64.f, acc);
    acc = fmaf(f1.w,   128.f, acc);
    acc = fmaf(f2.x,   256.f, acc);
    acc = fmaf(f2.y,   512.f, acc);
    acc = fmaf(f2.z,  1024.f, acc);
    acc = fmaf(f2.w,  2048.f, acc);
    acc = fmaf(f3.x,  4096.f, acc);
    acc = fmaf(f3.y,  8192.f, acc);
    acc = fmaf(f3.z, 16384.f, acc);
    acc = fmaf(f3.w, 32768.f, acc);
    return (unsigned)acc;
}

__global__ __launch_bounds__(256) void csa_fused(const float* __restrict__ x,
                                                 const int* __restrict__ mask,
                                                 float* __restrict__ out,
                                                 float* __restrict__ carry_out,
                                                 int B, int L) {
    int r = blockIdx.x * 256 + threadIdx.x;
    if (r >= B) return;
    const float4* row = reinterpret_cast<const float4*>(x) + (size_t)r * L * 4;

    unsigned in0 = pack16(row);
    unsigned tc  = pack16(row + 4);
    unsigned cnt = 0;
    for (int i = 2; i < L; ++i) {
        unsigned xi = pack16(row + (size_t)i * 4);
        unsigned s  = in0 ^ xi ^ tc;
        unsigned c  = (in0 & xi) | (tc & (in0 | xi));
        if (mask[i] > 0) {
            cnt += (c >> 15) & 1u;
            in0 = s;
            tc  = (c << 1) & 0xFFFFu;
        }
    }
    unsigned sum = in0 + tc;
    cnt += (sum >> 16) & 1u;

    float4* orow = reinterpret_cast<float4*>(out + (size_t)r * 16);
#pragma unroll
    for (int q = 0; q < 4; ++q) {
        float4 o;
        o.x = (float)((sum >> (q * 4 + 0)) & 1u);
        o.y = (float)((sum >> (q * 4 + 1)) & 1u);
        o.z = (float)((sum >> (q * 4 + 2)) & 1u);
        o.w = (float)((sum >> (q * 4 + 3)) & 1u);
        orow[q] = o;
    }
    carry_out[r] = (float)cnt;
}

extern "C" void kernel_launch(void* const* d_in, const int* in_sizes, int n_in,
                              void* d_out, int out_size, void* d_ws, size_t ws_size,
                              hipStream_t stream) {
    const float* x    = (const float*)d_in[0];
    const int*   mask = (const int*)d_in[1];
    float*       out  = (float*)d_out;

    const int L = in_sizes[1];                 // 64
    const int B = in_sizes[0] / (L * 16);      // 32768 (NBITS = 16)
    float* carry_out = out + (size_t)B * 16;

    if (L == 64 && (B % RPB) == 0) {
        csa_fused_block<<<dim3(B / RPB), dim3(256), 0, stream>>>(
            x, mask, out, carry_out, B);
    } else {
        csa_fused<<<dim3((unsigned)((B + 255) / 256)), dim3(256), 0, stream>>>(
            x, mask, out, carry_out, B, L);
    }
}